// Round 12
// baseline (2065.497 us; speedup 1.0000x reference)
//
#include <hip/hip_runtime.h>
#include <math.h>

#define REG_COEF 25.0f
#define B 8
#define H 3
#define N 4096

typedef _Float16 f16x8 __attribute__((ext_vector_type(8)));
typedef float f32x16 __attribute__((ext_vector_type(16)));

static constexpr int NX = B * N;          // 32768 sample points
static constexpr int NY = B * H * N;      // 98304 reflected points
static constexpr int NM = 2 * B * H * N;  // 196608 per-point mins

// Packed fragments for mfma_f32_32x32x16_f16 (32 B per point, 16 f16 slots):
//  A-pack (query, a=-2p): [ah(3) | al(3) | ah(3) | wh,wl | 1,1 | 0,0,0]
//  B-pack (target):       [th(3) | th(3) | tl(3) | 1,1 | twh,twl | 0,0,0]
//  dot(A,B) ~= |q-t|^2  (f16 hi/lo split, ~1e-4 abs err; verified R7-R11)
// ws layout (float units):
//   [0,       262144)  : ApkX   (1 MB)
//   [262144,  524288)  : BpkX   (1 MB)
//   [524288, 1310720)  : ApkY   (3 MB)
//   [1310720,2097152)  : BpkY   (3 MB)
//   [2097152,2293760)  : mins   (196608 floats)

__global__ void prep_kernel(const float* __restrict__ pts, const float* __restrict__ ypred,
                            char* __restrict__ ApkX, char* __restrict__ BpkX,
                            char* __restrict__ ApkY, char* __restrict__ BpkY,
                            float* __restrict__ mins, float* __restrict__ out)
{
    int idx = blockIdx.x * blockDim.x + threadIdx.x;
    if (idx == 0) {
        float reg = 0.f;
        for (int b = 0; b < B; ++b) {
            float n[H][3];
            #pragma unroll
            for (int h = 0; h < H; ++h) {
                float a0 = ypred[b * 12 + h * 4 + 0];
                float a1 = ypred[b * 12 + h * 4 + 1];
                float a2 = ypred[b * 12 + h * 4 + 2];
                float inv = rsqrtf(a0 * a0 + a1 * a1 + a2 * a2);
                n[h][0] = a0 * inv; n[h][1] = a1 * inv; n[h][2] = a2 * inv;
            }
            float s = 0.f;
            #pragma unroll
            for (int c = 0; c < H; ++c)
                #pragma unroll
                for (int e = 0; e < H; ++e) {
                    float g = n[c][0] * n[e][0] + n[c][1] * n[e][1] + n[c][2] * n[e][2];
                    if (c == e) g -= 1.f;
                    s += g * g;
                }
            reg += sqrtf(s);
        }
        out[0] = REG_COEF * reg;   // reduce_kernel accumulates on top
    }

    union { _Float16 h[16]; uint4 u[2]; } pa, pb;

    if (idx < NX) {
        const float* p = pts + (size_t)idx * 3;
        float x = p[0], y = p[1], z = p[2];
        float w = x * x + y * y + z * z;
        // A-pack of X
        float ax = -2.f * x, ay = -2.f * y, az = -2.f * z;
        _Float16 ahx = (_Float16)ax, ahy = (_Float16)ay, ahz = (_Float16)az;
        _Float16 wh = (_Float16)w;
        pa.h[0] = ahx; pa.h[1] = ahy; pa.h[2] = ahz;
        pa.h[3] = (_Float16)(ax - (float)ahx);
        pa.h[4] = (_Float16)(ay - (float)ahy);
        pa.h[5] = (_Float16)(az - (float)ahz);
        pa.h[6] = ahx; pa.h[7] = ahy; pa.h[8] = ahz;
        pa.h[9] = wh; pa.h[10] = (_Float16)(w - (float)wh);
        pa.h[11] = (_Float16)1.f; pa.h[12] = (_Float16)1.f;
        pa.h[13] = (_Float16)0.f; pa.h[14] = (_Float16)0.f; pa.h[15] = (_Float16)0.f;
        ((uint4*)(ApkX + (size_t)idx * 32))[0] = pa.u[0];
        ((uint4*)(ApkX + (size_t)idx * 32))[1] = pa.u[1];
        // B-pack of X
        _Float16 thx = (_Float16)x, thy = (_Float16)y, thz = (_Float16)z;
        pb.h[0] = thx; pb.h[1] = thy; pb.h[2] = thz;
        pb.h[3] = thx; pb.h[4] = thy; pb.h[5] = thz;
        pb.h[6] = (_Float16)(x - (float)thx);
        pb.h[7] = (_Float16)(y - (float)thy);
        pb.h[8] = (_Float16)(z - (float)thz);
        pb.h[9] = (_Float16)1.f; pb.h[10] = (_Float16)1.f;
        pb.h[11] = wh; pb.h[12] = (_Float16)(w - (float)wh);
        pb.h[13] = (_Float16)0.f; pb.h[14] = (_Float16)0.f; pb.h[15] = (_Float16)0.f;
        ((uint4*)(BpkX + (size_t)idx * 32))[0] = pb.u[0];
        ((uint4*)(BpkX + (size_t)idx * 32))[1] = pb.u[1];
    } else if (idx < NX + NY) {
        int t = idx - NX;            // (b*H + h)*N + nn
        int nn = t & (N - 1);
        int bh = t >> 12;
        int b = bh / H, h = bh - b * H;
        float a0 = ypred[b * 12 + h * 4 + 0];
        float a1 = ypred[b * 12 + h * 4 + 1];
        float a2 = ypred[b * 12 + h * 4 + 2];
        float off = ypred[b * 12 + h * 4 + 3];
        float inv = rsqrtf(a0 * a0 + a1 * a1 + a2 * a2);
        a0 *= inv; a1 *= inv; a2 *= inv;
        const float* p = pts + ((size_t)b * N + nn) * 3;
        float x0 = p[0], x1 = p[1], x2 = p[2];
        float dist = a0 * x0 + a1 * x1 + a2 * x2 + off;
        float x = fmaf(-2.f * dist, a0, x0);
        float y = fmaf(-2.f * dist, a1, x1);
        float z = fmaf(-2.f * dist, a2, x2);
        float w = x * x + y * y + z * z;
        // B-pack of Y
        _Float16 thx = (_Float16)x, thy = (_Float16)y, thz = (_Float16)z;
        _Float16 wh = (_Float16)w;
        pb.h[0] = thx; pb.h[1] = thy; pb.h[2] = thz;
        pb.h[3] = thx; pb.h[4] = thy; pb.h[5] = thz;
        pb.h[6] = (_Float16)(x - (float)thx);
        pb.h[7] = (_Float16)(y - (float)thy);
        pb.h[8] = (_Float16)(z - (float)thz);
        pb.h[9] = (_Float16)1.f; pb.h[10] = (_Float16)1.f;
        pb.h[11] = wh; pb.h[12] = (_Float16)(w - (float)wh);
        pb.h[13] = (_Float16)0.f; pb.h[14] = (_Float16)0.f; pb.h[15] = (_Float16)0.f;
        ((uint4*)(BpkY + (size_t)t * 32))[0] = pb.u[0];
        ((uint4*)(BpkY + (size_t)t * 32))[1] = pb.u[1];
        // A-pack of Y
        float ax = -2.f * x, ay = -2.f * y, az = -2.f * z;
        _Float16 ahx = (_Float16)ax, ahy = (_Float16)ay, ahz = (_Float16)az;
        pa.h[0] = ahx; pa.h[1] = ahy; pa.h[2] = ahz;
        pa.h[3] = (_Float16)(ax - (float)ahx);
        pa.h[4] = (_Float16)(ay - (float)ahy);
        pa.h[5] = (_Float16)(az - (float)ahz);
        pa.h[6] = ahx; pa.h[7] = ahy; pa.h[8] = ahz;
        pa.h[9] = wh; pa.h[10] = (_Float16)(w - (float)wh);
        pa.h[11] = (_Float16)1.f; pa.h[12] = (_Float16)1.f;
        pa.h[13] = (_Float16)0.f; pa.h[14] = (_Float16)0.f; pa.h[15] = (_Float16)0.f;
        ((uint4*)(ApkY + (size_t)t * 32))[0] = pa.u[0];
        ((uint4*)(ApkY + (size_t)t * 32))[1] = pa.u[1];
    } else if (idx < NX + NY + NM) {
        mins[idx - NX - NY] = __uint_as_float(0x7F800000u);  // +inf
    }
}

// 1536 blocks: [ts(2)][qs(16)][h(3)][b(8)][dir(2)]
// Block: 4 waves x 64 queries (2 A-frags). 2048 targets = 64 B-tiles,
// staged through LDS as 4 groups of 16 tiles (16 KB), double-buffered.
// Each wave DMAs 4 tiles/group via global_load_lds (1 instr = 1 KB tile,
// zero VGPR for in-flight data). Counted vmcnt(4), raw s_barrier.
// Compute: R9's pair-fold (4 MFMA + 32 v_min3 per tile-pair).
__global__ __launch_bounds__(256, 4) void chamfer_kernel(const char* __restrict__ ApkX,
                                                         const char* __restrict__ BpkX,
                                                         const char* __restrict__ ApkY,
                                                         const char* __restrict__ BpkY,
                                                         float* __restrict__ mins)
{
    __shared__ __align__(16) char smem[2][16384];

    int bid = blockIdx.x;
    int ts = bid & 1;
    int qs = (bid >> 1) & 15;
    int rest = bid >> 5;        // 0..47
    int hh = rest % 3;
    int tmp = rest / 3;         // 0..15
    int b = tmp & 7;
    int dir = tmp >> 3;

    int tid = threadIdx.x;
    int w = tid >> 6;
    int lane = tid & 63;
    int l31 = lane & 31, kb = lane >> 5;

    const char* Aq;
    const char* Bt;
    float* mq_base;
    if (dir == 0) {
        Aq = ApkX + (size_t)b * N * 32;
        Bt = BpkY + (size_t)(b * H + hh) * N * 32;
        mq_base = mins + (size_t)(b * H + hh) * N;
    } else {
        Aq = ApkY + (size_t)(b * H + hh) * N * 32;
        Bt = BpkX + (size_t)b * N * 32;
        mq_base = mins + (size_t)B * H * N + (size_t)(b * H + hh) * N;
    }
    int qbase = qs * 256 + w * 64;
    Aq += (size_t)qbase * 32;
    Bt += (size_t)ts * 2048 * 32;

    f16x8 A0 = *(const f16x8*)(Aq + ((size_t)(l31)) * 32 + kb * 16);
    f16x8 A1 = *(const f16x8*)(Aq + ((size_t)(32 + l31)) * 32 + kb * 16);

    f32x16 mq0, mq1;
    #pragma unroll
    for (int r = 0; r < 16; ++r) { mq0[r] = INFINITY; mq1[r] = INFINITY; }

    // DMA staging: wave w stages group-tiles {4w..4w+3}; 1 instr per 1 KB tile.
    const char* Bsrc = Bt + (size_t)(w * 4) * 1024 + (size_t)lane * 16;
    #define STAGE(g)                                                                      \
        {                                                                                 \
            char* dst0 = &smem[(g) & 1][w * 4096];                                        \
            const char* src0 = Bsrc + (size_t)(g) * 16384;                                \
            _Pragma("unroll")                                                             \
            for (int i = 0; i < 4; ++i)                                                   \
                __builtin_amdgcn_global_load_lds(                                         \
                    (const __attribute__((address_space(1))) void*)(src0 + (size_t)i * 1024), \
                    (__attribute__((address_space(3))) void*)(dst0 + i * 1024),           \
                    16, 0, 0);                                                            \
        }

    STAGE(0);
    STAGE(1);

    f32x16 zero = {};
    for (int g = 0; g < 4; ++g) {
        if (g < 3) asm volatile("s_waitcnt vmcnt(4)" ::: "memory");
        else       asm volatile("s_waitcnt vmcnt(0)" ::: "memory");
        __builtin_amdgcn_s_barrier();

        const char* lb = &smem[g & 1][(size_t)l31 * 32 + kb * 16];
        #pragma unroll
        for (int p = 0; p < 8; ++p) {
            f16x8 B0 = *(const f16x8*)(lb + (size_t)(2 * p) * 1024);
            f16x8 B1 = *(const f16x8*)(lb + (size_t)(2 * p + 1) * 1024);
            f32x16 D0 = __builtin_amdgcn_mfma_f32_32x32x16_f16(A0, B0, zero, 0, 0, 0);
            f32x16 D1 = __builtin_amdgcn_mfma_f32_32x32x16_f16(A0, B1, zero, 0, 0, 0);
            #pragma unroll
            for (int r = 0; r < 16; ++r)
                mq0[r] = fminf(mq0[r], fminf(D0[r], D1[r]));   // v_min3_f32
            f32x16 D2 = __builtin_amdgcn_mfma_f32_32x32x16_f16(A1, B0, zero, 0, 0, 0);
            f32x16 D3 = __builtin_amdgcn_mfma_f32_32x32x16_f16(A1, B1, zero, 0, 0, 0);
            #pragma unroll
            for (int r = 0; r < 16; ++r)
                mq1[r] = fminf(mq1[r], fminf(D2[r], D3[r]));   // v_min3_f32
        }

        asm volatile("s_waitcnt lgkmcnt(0)" ::: "memory");
        __builtin_amdgcn_s_barrier();
        if (g < 2) STAGE(g + 2);
    }
    #undef STAGE

    // reduce each query row across the 32 columns (lanes), then global atomicMin
    #pragma unroll
    for (int a = 0; a < 2; ++a) {
        #pragma unroll
        for (int r = 0; r < 16; ++r) {
            float v = (a == 0) ? mq0[r] : mq1[r];
            v = fminf(v, __shfl_xor(v, 1, 64));
            v = fminf(v, __shfl_xor(v, 2, 64));
            v = fminf(v, __shfl_xor(v, 4, 64));
            v = fminf(v, __shfl_xor(v, 8, 64));
            v = fminf(v, __shfl_xor(v, 16, 64));
            if (l31 == 0) {
                int row = (r & 3) + 8 * (r >> 2) + 4 * kb;
                atomicMin((unsigned*)&mq_base[qbase + a * 32 + row],
                          __float_as_uint(fmaxf(v, 0.f)));
            }
        }
    }
}

__global__ void reduce_kernel(const float* __restrict__ mins, float* __restrict__ out)
{
    int tid = blockIdx.x * blockDim.x + threadIdx.x;  // 192*256 = 49152 threads
    float s = 0.f;
    #pragma unroll
    for (int k = 0; k < 4; ++k) s += mins[tid + k * 49152];
    #pragma unroll
    for (int off = 32; off > 0; off >>= 1) s += __shfl_down(s, off);
    if ((threadIdx.x & 63) == 0) atomicAdd(out, s);
}

extern "C" void kernel_launch(void* const* d_in, const int* in_sizes, int n_in,
                              void* d_out, int out_size, void* d_ws, size_t ws_size,
                              hipStream_t stream)
{
    const float* pts = (const float*)d_in[0];   // (8,4096,3) fp32
    const float* yp  = (const float*)d_in[1];   // (8,3,4) fp32
    float* out = (float*)d_out;
    float* ws  = (float*)d_ws;

    char* ApkX = (char*)ws;                     // 1 MB
    char* BpkX = (char*)(ws + 262144);          // 1 MB
    char* ApkY = (char*)(ws + 524288);          // 3 MB
    char* BpkY = (char*)(ws + 1310720);         // 3 MB
    float* mins = ws + 2097152;                 // 196608 floats

    prep_kernel<<<1280, 256, 0, stream>>>(pts, yp, ApkX, BpkX, ApkY, BpkY, mins, out);
    chamfer_kernel<<<1536, 256, 0, stream>>>(ApkX, BpkX, ApkY, BpkY, mins);
    reduce_kernel<<<192, 256, 0, stream>>>(mins, out);
}

// Round 13
// 91.025 us; speedup vs baseline: 22.6916x; 22.6916x over previous
//
#include <hip/hip_runtime.h>
#include <math.h>

#define REG_COEF 25.0f
#define B 8
#define H 3
#define N 4096

typedef _Float16 f16x8 __attribute__((ext_vector_type(8)));
typedef float f32x16 __attribute__((ext_vector_type(16)));

static constexpr int NX = B * N;          // 32768 sample points
static constexpr int NY = B * H * N;      // 98304 reflected points
static constexpr int NM = 2 * B * H * N;  // 196608 per-point mins

// Packed fragments for mfma_f32_32x32x16_f16 (32 B per point, 16 f16 slots):
//  A-pack (query, a=-2p): [ah(3) | al(3) | ah(3) | wh,wl | 1,1 | 0,0,0]
//  B-pack (target):       [th(3) | th(3) | tl(3) | 1,1 | twh,twl | 0,0,0]
//  dot(A,B) ~= |q-t|^2  (f16 hi/lo split, ~1e-4 abs err; verified R7-R12)
// ws layout (float units):
//   [0,       262144)  : ApkX   (1 MB)
//   [262144,  524288)  : BpkX   (1 MB)
//   [524288, 1310720)  : ApkY   (3 MB)
//   [1310720,2097152)  : BpkY   (3 MB)
//   [2097152,2293760)  : mins   (196608 floats)

__global__ void prep_kernel(const float* __restrict__ pts, const float* __restrict__ ypred,
                            char* __restrict__ ApkX, char* __restrict__ BpkX,
                            char* __restrict__ ApkY, char* __restrict__ BpkY,
                            float* __restrict__ mins, float* __restrict__ out)
{
    int idx = blockIdx.x * blockDim.x + threadIdx.x;
    if (idx == 0) {
        float reg = 0.f;
        for (int b = 0; b < B; ++b) {
            float n[H][3];
            #pragma unroll
            for (int h = 0; h < H; ++h) {
                float a0 = ypred[b * 12 + h * 4 + 0];
                float a1 = ypred[b * 12 + h * 4 + 1];
                float a2 = ypred[b * 12 + h * 4 + 2];
                float inv = rsqrtf(a0 * a0 + a1 * a1 + a2 * a2);
                n[h][0] = a0 * inv; n[h][1] = a1 * inv; n[h][2] = a2 * inv;
            }
            float s = 0.f;
            #pragma unroll
            for (int c = 0; c < H; ++c)
                #pragma unroll
                for (int e = 0; e < H; ++e) {
                    float g = n[c][0] * n[e][0] + n[c][1] * n[e][1] + n[c][2] * n[e][2];
                    if (c == e) g -= 1.f;
                    s += g * g;
                }
            reg += sqrtf(s);
        }
        out[0] = REG_COEF * reg;   // reduce_kernel accumulates on top
    }

    union { _Float16 h[16]; uint4 u[2]; } pa, pb;

    if (idx < NX) {
        const float* p = pts + (size_t)idx * 3;
        float x = p[0], y = p[1], z = p[2];
        float w = x * x + y * y + z * z;
        // A-pack of X
        float ax = -2.f * x, ay = -2.f * y, az = -2.f * z;
        _Float16 ahx = (_Float16)ax, ahy = (_Float16)ay, ahz = (_Float16)az;
        _Float16 wh = (_Float16)w;
        pa.h[0] = ahx; pa.h[1] = ahy; pa.h[2] = ahz;
        pa.h[3] = (_Float16)(ax - (float)ahx);
        pa.h[4] = (_Float16)(ay - (float)ahy);
        pa.h[5] = (_Float16)(az - (float)ahz);
        pa.h[6] = ahx; pa.h[7] = ahy; pa.h[8] = ahz;
        pa.h[9] = wh; pa.h[10] = (_Float16)(w - (float)wh);
        pa.h[11] = (_Float16)1.f; pa.h[12] = (_Float16)1.f;
        pa.h[13] = (_Float16)0.f; pa.h[14] = (_Float16)0.f; pa.h[15] = (_Float16)0.f;
        ((uint4*)(ApkX + (size_t)idx * 32))[0] = pa.u[0];
        ((uint4*)(ApkX + (size_t)idx * 32))[1] = pa.u[1];
        // B-pack of X
        _Float16 thx = (_Float16)x, thy = (_Float16)y, thz = (_Float16)z;
        pb.h[0] = thx; pb.h[1] = thy; pb.h[2] = thz;
        pb.h[3] = thx; pb.h[4] = thy; pb.h[5] = thz;
        pb.h[6] = (_Float16)(x - (float)thx);
        pb.h[7] = (_Float16)(y - (float)thy);
        pb.h[8] = (_Float16)(z - (float)thz);
        pb.h[9] = (_Float16)1.f; pb.h[10] = (_Float16)1.f;
        pb.h[11] = wh; pb.h[12] = (_Float16)(w - (float)wh);
        pb.h[13] = (_Float16)0.f; pb.h[14] = (_Float16)0.f; pb.h[15] = (_Float16)0.f;
        ((uint4*)(BpkX + (size_t)idx * 32))[0] = pb.u[0];
        ((uint4*)(BpkX + (size_t)idx * 32))[1] = pb.u[1];
    } else if (idx < NX + NY) {
        int t = idx - NX;            // (b*H + h)*N + nn
        int nn = t & (N - 1);
        int bh = t >> 12;
        int b = bh / H, h = bh - b * H;
        float a0 = ypred[b * 12 + h * 4 + 0];
        float a1 = ypred[b * 12 + h * 4 + 1];
        float a2 = ypred[b * 12 + h * 4 + 2];
        float off = ypred[b * 12 + h * 4 + 3];
        float inv = rsqrtf(a0 * a0 + a1 * a1 + a2 * a2);
        a0 *= inv; a1 *= inv; a2 *= inv;
        const float* p = pts + ((size_t)b * N + nn) * 3;
        float x0 = p[0], x1 = p[1], x2 = p[2];
        float dist = a0 * x0 + a1 * x1 + a2 * x2 + off;
        float x = fmaf(-2.f * dist, a0, x0);
        float y = fmaf(-2.f * dist, a1, x1);
        float z = fmaf(-2.f * dist, a2, x2);
        float w = x * x + y * y + z * z;
        // B-pack of Y
        _Float16 thx = (_Float16)x, thy = (_Float16)y, thz = (_Float16)z;
        _Float16 wh = (_Float16)w;
        pb.h[0] = thx; pb.h[1] = thy; pb.h[2] = thz;
        pb.h[3] = thx; pb.h[4] = thy; pb.h[5] = thz;
        pb.h[6] = (_Float16)(x - (float)thx);
        pb.h[7] = (_Float16)(y - (float)thy);
        pb.h[8] = (_Float16)(z - (float)thz);
        pb.h[9] = (_Float16)1.f; pb.h[10] = (_Float16)1.f;
        pb.h[11] = wh; pb.h[12] = (_Float16)(w - (float)wh);
        pb.h[13] = (_Float16)0.f; pb.h[14] = (_Float16)0.f; pb.h[15] = (_Float16)0.f;
        ((uint4*)(BpkY + (size_t)t * 32))[0] = pb.u[0];
        ((uint4*)(BpkY + (size_t)t * 32))[1] = pb.u[1];
        // A-pack of Y
        float ax = -2.f * x, ay = -2.f * y, az = -2.f * z;
        _Float16 ahx = (_Float16)ax, ahy = (_Float16)ay, ahz = (_Float16)az;
        pa.h[0] = ahx; pa.h[1] = ahy; pa.h[2] = ahz;
        pa.h[3] = (_Float16)(ax - (float)ahx);
        pa.h[4] = (_Float16)(ay - (float)ahy);
        pa.h[5] = (_Float16)(az - (float)ahz);
        pa.h[6] = ahx; pa.h[7] = ahy; pa.h[8] = ahz;
        pa.h[9] = wh; pa.h[10] = (_Float16)(w - (float)wh);
        pa.h[11] = (_Float16)1.f; pa.h[12] = (_Float16)1.f;
        pa.h[13] = (_Float16)0.f; pa.h[14] = (_Float16)0.f; pa.h[15] = (_Float16)0.f;
        ((uint4*)(ApkY + (size_t)t * 32))[0] = pa.u[0];
        ((uint4*)(ApkY + (size_t)t * 32))[1] = pa.u[1];
    } else if (idx < NX + NY + NM) {
        mins[idx - NX - NY] = __uint_as_float(0x7F800000u);  // +inf
    }
}

// 1536 blocks: [ts(2)][qs(16)][h(3)][b(8)][dir(2)]
// Block: 4 waves x 64 queries (2 A-frags). 2048 targets = 64 B-tiles,
// consumed as 4 groups of 16 tiles (16 KB) staged in LDS by registers:
//   ds_write group g -> issue group g+1 global loads (hide under compute)
//   -> sync -> compute 16 tiles (32 MFMA + 256 v_min3) -> sync.
// Plain HIP: compiler manages all waitcnts. No inline asm (R12 lesson).
__global__ __launch_bounds__(256, 2) void chamfer_kernel(const char* __restrict__ ApkX,
                                                         const char* __restrict__ BpkX,
                                                         const char* __restrict__ ApkY,
                                                         const char* __restrict__ BpkY,
                                                         float* __restrict__ mins)
{
    __shared__ __align__(16) uint4 smem[1024];   // 16 KB, single buffer

    int bid = blockIdx.x;
    int ts = bid & 1;
    int qs = (bid >> 1) & 15;
    int rest = bid >> 5;        // 0..47
    int hh = rest % 3;
    int tmp = rest / 3;         // 0..15
    int b = tmp & 7;
    int dir = tmp >> 3;

    int tid = threadIdx.x;
    int w = tid >> 6;
    int lane = tid & 63;
    int l31 = lane & 31, kb = lane >> 5;

    const char* Aq;
    const char* Bt;
    float* mq_base;
    if (dir == 0) {
        Aq = ApkX + (size_t)b * N * 32;
        Bt = BpkY + (size_t)(b * H + hh) * N * 32;
        mq_base = mins + (size_t)(b * H + hh) * N;
    } else {
        Aq = ApkY + (size_t)(b * H + hh) * N * 32;
        Bt = BpkX + (size_t)b * N * 32;
        mq_base = mins + (size_t)B * H * N + (size_t)(b * H + hh) * N;
    }
    int qbase = qs * 256 + w * 64;
    Aq += (size_t)qbase * 32;
    Bt += (size_t)ts * 2048 * 32;

    f16x8 A0 = *(const f16x8*)(Aq + ((size_t)(l31)) * 32 + kb * 16);
    f16x8 A1 = *(const f16x8*)(Aq + ((size_t)(32 + l31)) * 32 + kb * 16);

    f32x16 mq0, mq1;
    #pragma unroll
    for (int r = 0; r < 16; ++r) { mq0[r] = INFINITY; mq1[r] = INFINITY; }

    const uint4* Bsrc = (const uint4*)Bt;   // 4096 uint4 = 64 tiles
    uint4 st[4];
    #pragma unroll
    for (int i = 0; i < 4; ++i) st[i] = Bsrc[tid + 256 * i];

    f32x16 zero = {};
    for (int g = 0; g < 4; ++g) {
        // write staged group to LDS
        #pragma unroll
        for (int i = 0; i < 4; ++i) smem[tid + 256 * i] = st[i];
        // issue next group's global loads now; latency hides under compute
        if (g < 3) {
            #pragma unroll
            for (int i = 0; i < 4; ++i) st[i] = Bsrc[(g + 1) * 1024 + tid + 256 * i];
        }
        __syncthreads();

        const char* lb = (const char*)smem + (size_t)l31 * 32 + kb * 16;
        #pragma unroll
        for (int p = 0; p < 8; ++p) {
            f16x8 B0 = *(const f16x8*)(lb + (size_t)(2 * p) * 1024);
            f16x8 B1 = *(const f16x8*)(lb + (size_t)(2 * p + 1) * 1024);
            f32x16 D0 = __builtin_amdgcn_mfma_f32_32x32x16_f16(A0, B0, zero, 0, 0, 0);
            f32x16 D1 = __builtin_amdgcn_mfma_f32_32x32x16_f16(A0, B1, zero, 0, 0, 0);
            #pragma unroll
            for (int r = 0; r < 16; ++r)
                mq0[r] = fminf(mq0[r], fminf(D0[r], D1[r]));   // v_min3_f32
            f32x16 D2 = __builtin_amdgcn_mfma_f32_32x32x16_f16(A1, B0, zero, 0, 0, 0);
            f32x16 D3 = __builtin_amdgcn_mfma_f32_32x32x16_f16(A1, B1, zero, 0, 0, 0);
            #pragma unroll
            for (int r = 0; r < 16; ++r)
                mq1[r] = fminf(mq1[r], fminf(D2[r], D3[r]));   // v_min3_f32
        }
        __syncthreads();
    }

    // reduce each query row across the 32 columns (lanes), then global atomicMin
    #pragma unroll
    for (int a = 0; a < 2; ++a) {
        #pragma unroll
        for (int r = 0; r < 16; ++r) {
            float v = (a == 0) ? mq0[r] : mq1[r];
            v = fminf(v, __shfl_xor(v, 1, 64));
            v = fminf(v, __shfl_xor(v, 2, 64));
            v = fminf(v, __shfl_xor(v, 4, 64));
            v = fminf(v, __shfl_xor(v, 8, 64));
            v = fminf(v, __shfl_xor(v, 16, 64));
            if (l31 == 0) {
                int row = (r & 3) + 8 * (r >> 2) + 4 * kb;
                atomicMin((unsigned*)&mq_base[qbase + a * 32 + row],
                          __float_as_uint(fmaxf(v, 0.f)));
            }
        }
    }
}

__global__ void reduce_kernel(const float* __restrict__ mins, float* __restrict__ out)
{
    int tid = blockIdx.x * blockDim.x + threadIdx.x;  // 192*256 = 49152 threads
    float s = 0.f;
    #pragma unroll
    for (int k = 0; k < 4; ++k) s += mins[tid + k * 49152];
    #pragma unroll
    for (int off = 32; off > 0; off >>= 1) s += __shfl_down(s, off);
    if ((threadIdx.x & 63) == 0) atomicAdd(out, s);
}

extern "C" void kernel_launch(void* const* d_in, const int* in_sizes, int n_in,
                              void* d_out, int out_size, void* d_ws, size_t ws_size,
                              hipStream_t stream)
{
    const float* pts = (const float*)d_in[0];   // (8,4096,3) fp32
    const float* yp  = (const float*)d_in[1];   // (8,3,4) fp32
    float* out = (float*)d_out;
    float* ws  = (float*)d_ws;

    char* ApkX = (char*)ws;                     // 1 MB
    char* BpkX = (char*)(ws + 262144);          // 1 MB
    char* ApkY = (char*)(ws + 524288);          // 3 MB
    char* BpkY = (char*)(ws + 1310720);         // 3 MB
    float* mins = ws + 2097152;                 // 196608 floats

    prep_kernel<<<1280, 256, 0, stream>>>(pts, yp, ApkX, BpkX, ApkY, BpkY, mins, out);
    chamfer_kernel<<<1536, 256, 0, stream>>>(ApkX, BpkX, ApkY, BpkY, mins);
    reduce_kernel<<<192, 256, 0, stream>>>(mins, out);
}

// Round 14
// 90.656 us; speedup vs baseline: 22.7839x; 1.0041x over previous
//
#include <hip/hip_runtime.h>
#include <math.h>

#define REG_COEF 25.0f
#define B 8
#define H 3
#define N 4096

typedef _Float16 f16x8 __attribute__((ext_vector_type(8)));
typedef float f32x16 __attribute__((ext_vector_type(16)));

static constexpr int NX = B * N;          // 32768 sample points
static constexpr int NY = B * H * N;      // 98304 reflected points
static constexpr int NM = 2 * B * H * N;  // 196608 per-point mins

// Packed fragments for mfma_f32_32x32x16_f16 (32 B per point, 16 f16 slots):
//  A-pack (query, a=-2p): [ah(3) | al(3) | ah(3) | wh,wl | 1,1 | 0,0,0]
//  B-pack (target):       [th(3) | th(3) | tl(3) | 1,1 | twh,twl | 0,0,0]
//  dot(A,B) ~= |q-t|^2  (f16 hi/lo split, ~1e-4 abs err; verified R7-R13)
// B arrays use TILE-SPLIT layout (R14): each 32-point tile = 1 KB stored as
//  [32 x 16B kb=0 halves][32 x 16B kb=1 halves]  -> LDS reads are
//  16-consecutive-lanes -> 16-consecutive-chunks = conflict-free.
// A arrays stay point-major (read once per block, direct from global).
// ws layout (float units):
//   [0,       262144)  : ApkX   (1 MB)
//   [262144,  524288)  : BpkX   (1 MB)
//   [524288, 1310720)  : ApkY   (3 MB)
//   [1310720,2097152)  : BpkY   (3 MB)
//   [2097152,2293760)  : mins   (196608 floats)

__global__ void prep_kernel(const float* __restrict__ pts, const float* __restrict__ ypred,
                            char* __restrict__ ApkX, char* __restrict__ BpkX,
                            char* __restrict__ ApkY, char* __restrict__ BpkY,
                            float* __restrict__ mins, float* __restrict__ out)
{
    int idx = blockIdx.x * blockDim.x + threadIdx.x;
    if (idx == 0) {
        float reg = 0.f;
        for (int b = 0; b < B; ++b) {
            float n[H][3];
            #pragma unroll
            for (int h = 0; h < H; ++h) {
                float a0 = ypred[b * 12 + h * 4 + 0];
                float a1 = ypred[b * 12 + h * 4 + 1];
                float a2 = ypred[b * 12 + h * 4 + 2];
                float inv = rsqrtf(a0 * a0 + a1 * a1 + a2 * a2);
                n[h][0] = a0 * inv; n[h][1] = a1 * inv; n[h][2] = a2 * inv;
            }
            float s = 0.f;
            #pragma unroll
            for (int c = 0; c < H; ++c)
                #pragma unroll
                for (int e = 0; e < H; ++e) {
                    float g = n[c][0] * n[e][0] + n[c][1] * n[e][1] + n[c][2] * n[e][2];
                    if (c == e) g -= 1.f;
                    s += g * g;
                }
            reg += sqrtf(s);
        }
        out[0] = REG_COEF * reg;   // reduce_kernel accumulates on top
    }

    union { _Float16 h[16]; uint4 u[2]; } pa, pb;

    if (idx < NX) {
        const float* p = pts + (size_t)idx * 3;
        float x = p[0], y = p[1], z = p[2];
        float w = x * x + y * y + z * z;
        // A-pack of X
        float ax = -2.f * x, ay = -2.f * y, az = -2.f * z;
        _Float16 ahx = (_Float16)ax, ahy = (_Float16)ay, ahz = (_Float16)az;
        _Float16 wh = (_Float16)w;
        pa.h[0] = ahx; pa.h[1] = ahy; pa.h[2] = ahz;
        pa.h[3] = (_Float16)(ax - (float)ahx);
        pa.h[4] = (_Float16)(ay - (float)ahy);
        pa.h[5] = (_Float16)(az - (float)ahz);
        pa.h[6] = ahx; pa.h[7] = ahy; pa.h[8] = ahz;
        pa.h[9] = wh; pa.h[10] = (_Float16)(w - (float)wh);
        pa.h[11] = (_Float16)1.f; pa.h[12] = (_Float16)1.f;
        pa.h[13] = (_Float16)0.f; pa.h[14] = (_Float16)0.f; pa.h[15] = (_Float16)0.f;
        ((uint4*)(ApkX + (size_t)idx * 32))[0] = pa.u[0];
        ((uint4*)(ApkX + (size_t)idx * 32))[1] = pa.u[1];
        // B-pack of X, tile-split layout
        _Float16 thx = (_Float16)x, thy = (_Float16)y, thz = (_Float16)z;
        pb.h[0] = thx; pb.h[1] = thy; pb.h[2] = thz;
        pb.h[3] = thx; pb.h[4] = thy; pb.h[5] = thz;
        pb.h[6] = (_Float16)(x - (float)thx);
        pb.h[7] = (_Float16)(y - (float)thy);
        pb.h[8] = (_Float16)(z - (float)thz);
        pb.h[9] = (_Float16)1.f; pb.h[10] = (_Float16)1.f;
        pb.h[11] = wh; pb.h[12] = (_Float16)(w - (float)wh);
        pb.h[13] = (_Float16)0.f; pb.h[14] = (_Float16)0.f; pb.h[15] = (_Float16)0.f;
        int tile = idx >> 5, pos = idx & 31;
        ((uint4*)BpkX)[tile * 64 + pos]      = pb.u[0];
        ((uint4*)BpkX)[tile * 64 + 32 + pos] = pb.u[1];
    } else if (idx < NX + NY) {
        int t = idx - NX;            // (b*H + h)*N + nn
        int nn = t & (N - 1);
        int bh = t >> 12;
        int b = bh / H, h = bh - b * H;
        float a0 = ypred[b * 12 + h * 4 + 0];
        float a1 = ypred[b * 12 + h * 4 + 1];
        float a2 = ypred[b * 12 + h * 4 + 2];
        float off = ypred[b * 12 + h * 4 + 3];
        float inv = rsqrtf(a0 * a0 + a1 * a1 + a2 * a2);
        a0 *= inv; a1 *= inv; a2 *= inv;
        const float* p = pts + ((size_t)b * N + nn) * 3;
        float x0 = p[0], x1 = p[1], x2 = p[2];
        float dist = a0 * x0 + a1 * x1 + a2 * x2 + off;
        float x = fmaf(-2.f * dist, a0, x0);
        float y = fmaf(-2.f * dist, a1, x1);
        float z = fmaf(-2.f * dist, a2, x2);
        float w = x * x + y * y + z * z;
        // B-pack of Y, tile-split layout
        _Float16 thx = (_Float16)x, thy = (_Float16)y, thz = (_Float16)z;
        _Float16 wh = (_Float16)w;
        pb.h[0] = thx; pb.h[1] = thy; pb.h[2] = thz;
        pb.h[3] = thx; pb.h[4] = thy; pb.h[5] = thz;
        pb.h[6] = (_Float16)(x - (float)thx);
        pb.h[7] = (_Float16)(y - (float)thy);
        pb.h[8] = (_Float16)(z - (float)thz);
        pb.h[9] = (_Float16)1.f; pb.h[10] = (_Float16)1.f;
        pb.h[11] = wh; pb.h[12] = (_Float16)(w - (float)wh);
        pb.h[13] = (_Float16)0.f; pb.h[14] = (_Float16)0.f; pb.h[15] = (_Float16)0.f;
        int tile = t >> 5, pos = t & 31;
        ((uint4*)BpkY)[tile * 64 + pos]      = pb.u[0];
        ((uint4*)BpkY)[tile * 64 + 32 + pos] = pb.u[1];
        // A-pack of Y
        float ax = -2.f * x, ay = -2.f * y, az = -2.f * z;
        _Float16 ahx = (_Float16)ax, ahy = (_Float16)ay, ahz = (_Float16)az;
        pa.h[0] = ahx; pa.h[1] = ahy; pa.h[2] = ahz;
        pa.h[3] = (_Float16)(ax - (float)ahx);
        pa.h[4] = (_Float16)(ay - (float)ahy);
        pa.h[5] = (_Float16)(az - (float)ahz);
        pa.h[6] = ahx; pa.h[7] = ahy; pa.h[8] = ahz;
        pa.h[9] = wh; pa.h[10] = (_Float16)(w - (float)wh);
        pa.h[11] = (_Float16)1.f; pa.h[12] = (_Float16)1.f;
        pa.h[13] = (_Float16)0.f; pa.h[14] = (_Float16)0.f; pa.h[15] = (_Float16)0.f;
        ((uint4*)(ApkY + (size_t)t * 32))[0] = pa.u[0];
        ((uint4*)(ApkY + (size_t)t * 32))[1] = pa.u[1];
    } else if (idx < NX + NY + NM) {
        mins[idx - NX - NY] = __uint_as_float(0x7F800000u);  // +inf
    }
}

// 1536 blocks: [ts(2)][qs(16)][h(3)][b(8)][dir(2)]
// Block: 4 waves x 64 queries (2 A-frags). 2048 targets = 64 B-tiles,
// consumed as 4 groups of 16 tiles (16 KB) staged in LDS by registers:
//   ds_write group g -> issue group g+1 global loads (hide under compute)
//   -> sync -> compute 16 tiles (32 MFMA + 256 v_min3) -> sync.
// Tile-split layout makes every ds_read_b128 conflict-free (R14 fix).
__global__ __launch_bounds__(256, 2) void chamfer_kernel(const char* __restrict__ ApkX,
                                                         const char* __restrict__ BpkX,
                                                         const char* __restrict__ ApkY,
                                                         const char* __restrict__ BpkY,
                                                         float* __restrict__ mins)
{
    __shared__ __align__(16) uint4 smem[1024];   // 16 KB, single buffer

    int bid = blockIdx.x;
    int ts = bid & 1;
    int qs = (bid >> 1) & 15;
    int rest = bid >> 5;        // 0..47
    int hh = rest % 3;
    int tmp = rest / 3;         // 0..15
    int b = tmp & 7;
    int dir = tmp >> 3;

    int tid = threadIdx.x;
    int w = tid >> 6;
    int lane = tid & 63;
    int l31 = lane & 31, kb = lane >> 5;

    const char* Aq;
    const char* Bt;
    float* mq_base;
    if (dir == 0) {
        Aq = ApkX + (size_t)b * N * 32;
        Bt = BpkY + (size_t)(b * H + hh) * N * 32;
        mq_base = mins + (size_t)(b * H + hh) * N;
    } else {
        Aq = ApkY + (size_t)(b * H + hh) * N * 32;
        Bt = BpkX + (size_t)b * N * 32;
        mq_base = mins + (size_t)B * H * N + (size_t)(b * H + hh) * N;
    }
    int qbase = qs * 256 + w * 64;
    Aq += (size_t)qbase * 32;
    Bt += (size_t)ts * 2048 * 32;

    f16x8 A0 = *(const f16x8*)(Aq + ((size_t)(l31)) * 32 + kb * 16);
    f16x8 A1 = *(const f16x8*)(Aq + ((size_t)(32 + l31)) * 32 + kb * 16);

    f32x16 mq0, mq1;
    #pragma unroll
    for (int r = 0; r < 16; ++r) { mq0[r] = INFINITY; mq1[r] = INFINITY; }

    const uint4* Bsrc = (const uint4*)Bt;   // 4096 uint4 = 64 tile-split tiles
    uint4 st[4];
    #pragma unroll
    for (int i = 0; i < 4; ++i) st[i] = Bsrc[tid + 256 * i];

    f32x16 zero = {};
    for (int g = 0; g < 4; ++g) {
        // write staged group to LDS (linear, conflict-free)
        #pragma unroll
        for (int i = 0; i < 4; ++i) smem[tid + 256 * i] = st[i];
        // issue next group's global loads now; latency hides under compute
        if (g < 3) {
            #pragma unroll
            for (int i = 0; i < 4; ++i) st[i] = Bsrc[(g + 1) * 1024 + tid + 256 * i];
        }
        __syncthreads();

        // lane (l31,kb) reads chunk kb*32+l31 of each tile: contiguous per
        // 16-lane cycle group -> zero bank conflicts.
        const char* lb = (const char*)smem + (size_t)kb * 512 + (size_t)l31 * 16;
        #pragma unroll
        for (int p = 0; p < 8; ++p) {
            f16x8 B0 = *(const f16x8*)(lb + (size_t)(2 * p) * 1024);
            f16x8 B1 = *(const f16x8*)(lb + (size_t)(2 * p + 1) * 1024);
            f32x16 D0 = __builtin_amdgcn_mfma_f32_32x32x16_f16(A0, B0, zero, 0, 0, 0);
            f32x16 D1 = __builtin_amdgcn_mfma_f32_32x32x16_f16(A0, B1, zero, 0, 0, 0);
            #pragma unroll
            for (int r = 0; r < 16; ++r)
                mq0[r] = fminf(mq0[r], fminf(D0[r], D1[r]));   // v_min3_f32
            f32x16 D2 = __builtin_amdgcn_mfma_f32_32x32x16_f16(A1, B0, zero, 0, 0, 0);
            f32x16 D3 = __builtin_amdgcn_mfma_f32_32x32x16_f16(A1, B1, zero, 0, 0, 0);
            #pragma unroll
            for (int r = 0; r < 16; ++r)
                mq1[r] = fminf(mq1[r], fminf(D2[r], D3[r]));   // v_min3_f32
        }
        __syncthreads();
    }

    // reduce each query row across the 32 columns (lanes), then global atomicMin
    #pragma unroll
    for (int a = 0; a < 2; ++a) {
        #pragma unroll
        for (int r = 0; r < 16; ++r) {
            float v = (a == 0) ? mq0[r] : mq1[r];
            v = fminf(v, __shfl_xor(v, 1, 64));
            v = fminf(v, __shfl_xor(v, 2, 64));
            v = fminf(v, __shfl_xor(v, 4, 64));
            v = fminf(v, __shfl_xor(v, 8, 64));
            v = fminf(v, __shfl_xor(v, 16, 64));
            if (l31 == 0) {
                int row = (r & 3) + 8 * (r >> 2) + 4 * kb;
                atomicMin((unsigned*)&mq_base[qbase + a * 32 + row],
                          __float_as_uint(fmaxf(v, 0.f)));
            }
        }
    }
}

__global__ void reduce_kernel(const float* __restrict__ mins, float* __restrict__ out)
{
    int tid = blockIdx.x * blockDim.x + threadIdx.x;  // 192*256 = 49152 threads
    float s = 0.f;
    #pragma unroll
    for (int k = 0; k < 4; ++k) s += mins[tid + k * 49152];
    #pragma unroll
    for (int off = 32; off > 0; off >>= 1) s += __shfl_down(s, off);
    if ((threadIdx.x & 63) == 0) atomicAdd(out, s);
}

extern "C" void kernel_launch(void* const* d_in, const int* in_sizes, int n_in,
                              void* d_out, int out_size, void* d_ws, size_t ws_size,
                              hipStream_t stream)
{
    const float* pts = (const float*)d_in[0];   // (8,4096,3) fp32
    const float* yp  = (const float*)d_in[1];   // (8,3,4) fp32
    float* out = (float*)d_out;
    float* ws  = (float*)d_ws;

    char* ApkX = (char*)ws;                     // 1 MB
    char* BpkX = (char*)(ws + 262144);          // 1 MB
    char* ApkY = (char*)(ws + 524288);          // 3 MB
    char* BpkY = (char*)(ws + 1310720);         // 3 MB
    float* mins = ws + 2097152;                 // 196608 floats

    prep_kernel<<<1280, 256, 0, stream>>>(pts, yp, ApkX, BpkX, ApkY, BpkY, mins, out);
    chamfer_kernel<<<1536, 256, 0, stream>>>(ApkX, BpkX, ApkY, BpkY, mins);
    reduce_kernel<<<192, 256, 0, stream>>>(mins, out);
}

// Round 15
// 78.094 us; speedup vs baseline: 26.4488x; 1.1609x over previous
//
#include <hip/hip_runtime.h>
#include <math.h>

#define REG_COEF 25.0f
#define B 8
#define H 3
#define N 4096

typedef _Float16 f16x8 __attribute__((ext_vector_type(8)));
typedef float f32x16 __attribute__((ext_vector_type(16)));

static constexpr int NX = B * N;          // 32768 sample points
static constexpr int NY = B * H * N;      // 98304 reflected points
static constexpr int NM = 2 * B * H * N;  // 196608 per-point mins

// Packed fragments for mfma_f32_32x32x16_f16 (32 B per point, 16 f16 slots):
//  A-pack (query, a=-2p): [ah(3) | al(3) | ah(3) | wh,wl | 1,1 | 0,0,0]
//  B-pack (target):       [th(3) | th(3) | tl(3) | 1,1 | twh,twl | 0,0,0]
//  dot(A,B) ~= |q-t|^2  (f16 hi/lo split, ~1e-4 abs err; verified R7-R14)
// B arrays use TILE-SPLIT layout (R14): each 32-point tile = 1 KB stored as
//  [32 x 16B kb=0 halves][32 x 16B kb=1 halves]. Linear global_load_lds DMA
//  preserves it in LDS -> conflict-free ds_read_b128 (measured 0 in R14).
// ws layout (float units):
//   [0,       262144)  : ApkX   (1 MB)
//   [262144,  524288)  : BpkX   (1 MB)
//   [524288, 1310720)  : ApkY   (3 MB)
//   [1310720,2097152)  : BpkY   (3 MB)
//   [2097152,2293760)  : mins   (196608 floats)

__global__ void prep_kernel(const float* __restrict__ pts, const float* __restrict__ ypred,
                            char* __restrict__ ApkX, char* __restrict__ BpkX,
                            char* __restrict__ ApkY, char* __restrict__ BpkY,
                            float* __restrict__ mins, float* __restrict__ out)
{
    int idx = blockIdx.x * blockDim.x + threadIdx.x;
    if (idx == 0) {
        float reg = 0.f;
        for (int b = 0; b < B; ++b) {
            float n[H][3];
            #pragma unroll
            for (int h = 0; h < H; ++h) {
                float a0 = ypred[b * 12 + h * 4 + 0];
                float a1 = ypred[b * 12 + h * 4 + 1];
                float a2 = ypred[b * 12 + h * 4 + 2];
                float inv = rsqrtf(a0 * a0 + a1 * a1 + a2 * a2);
                n[h][0] = a0 * inv; n[h][1] = a1 * inv; n[h][2] = a2 * inv;
            }
            float s = 0.f;
            #pragma unroll
            for (int c = 0; c < H; ++c)
                #pragma unroll
                for (int e = 0; e < H; ++e) {
                    float g = n[c][0] * n[e][0] + n[c][1] * n[e][1] + n[c][2] * n[e][2];
                    if (c == e) g -= 1.f;
                    s += g * g;
                }
            reg += sqrtf(s);
        }
        out[0] = REG_COEF * reg;   // reduce_kernel accumulates on top
    }

    union { _Float16 h[16]; uint4 u[2]; } pa, pb;

    if (idx < NX) {
        const float* p = pts + (size_t)idx * 3;
        float x = p[0], y = p[1], z = p[2];
        float w = x * x + y * y + z * z;
        // A-pack of X
        float ax = -2.f * x, ay = -2.f * y, az = -2.f * z;
        _Float16 ahx = (_Float16)ax, ahy = (_Float16)ay, ahz = (_Float16)az;
        _Float16 wh = (_Float16)w;
        pa.h[0] = ahx; pa.h[1] = ahy; pa.h[2] = ahz;
        pa.h[3] = (_Float16)(ax - (float)ahx);
        pa.h[4] = (_Float16)(ay - (float)ahy);
        pa.h[5] = (_Float16)(az - (float)ahz);
        pa.h[6] = ahx; pa.h[7] = ahy; pa.h[8] = ahz;
        pa.h[9] = wh; pa.h[10] = (_Float16)(w - (float)wh);
        pa.h[11] = (_Float16)1.f; pa.h[12] = (_Float16)1.f;
        pa.h[13] = (_Float16)0.f; pa.h[14] = (_Float16)0.f; pa.h[15] = (_Float16)0.f;
        ((uint4*)(ApkX + (size_t)idx * 32))[0] = pa.u[0];
        ((uint4*)(ApkX + (size_t)idx * 32))[1] = pa.u[1];
        // B-pack of X, tile-split layout
        _Float16 thx = (_Float16)x, thy = (_Float16)y, thz = (_Float16)z;
        pb.h[0] = thx; pb.h[1] = thy; pb.h[2] = thz;
        pb.h[3] = thx; pb.h[4] = thy; pb.h[5] = thz;
        pb.h[6] = (_Float16)(x - (float)thx);
        pb.h[7] = (_Float16)(y - (float)thy);
        pb.h[8] = (_Float16)(z - (float)thz);
        pb.h[9] = (_Float16)1.f; pb.h[10] = (_Float16)1.f;
        pb.h[11] = wh; pb.h[12] = (_Float16)(w - (float)wh);
        pb.h[13] = (_Float16)0.f; pb.h[14] = (_Float16)0.f; pb.h[15] = (_Float16)0.f;
        int tile = idx >> 5, pos = idx & 31;
        ((uint4*)BpkX)[tile * 64 + pos]      = pb.u[0];
        ((uint4*)BpkX)[tile * 64 + 32 + pos] = pb.u[1];
    } else if (idx < NX + NY) {
        int t = idx - NX;            // (b*H + h)*N + nn
        int nn = t & (N - 1);
        int bh = t >> 12;
        int b = bh / H, h = bh - b * H;
        float a0 = ypred[b * 12 + h * 4 + 0];
        float a1 = ypred[b * 12 + h * 4 + 1];
        float a2 = ypred[b * 12 + h * 4 + 2];
        float off = ypred[b * 12 + h * 4 + 3];
        float inv = rsqrtf(a0 * a0 + a1 * a1 + a2 * a2);
        a0 *= inv; a1 *= inv; a2 *= inv;
        const float* p = pts + ((size_t)b * N + nn) * 3;
        float x0 = p[0], x1 = p[1], x2 = p[2];
        float dist = a0 * x0 + a1 * x1 + a2 * x2 + off;
        float x = fmaf(-2.f * dist, a0, x0);
        float y = fmaf(-2.f * dist, a1, x1);
        float z = fmaf(-2.f * dist, a2, x2);
        float w = x * x + y * y + z * z;
        // B-pack of Y, tile-split layout
        _Float16 thx = (_Float16)x, thy = (_Float16)y, thz = (_Float16)z;
        _Float16 wh = (_Float16)w;
        pb.h[0] = thx; pb.h[1] = thy; pb.h[2] = thz;
        pb.h[3] = thx; pb.h[4] = thy; pb.h[5] = thz;
        pb.h[6] = (_Float16)(x - (float)thx);
        pb.h[7] = (_Float16)(y - (float)thy);
        pb.h[8] = (_Float16)(z - (float)thz);
        pb.h[9] = (_Float16)1.f; pb.h[10] = (_Float16)1.f;
        pb.h[11] = wh; pb.h[12] = (_Float16)(w - (float)wh);
        pb.h[13] = (_Float16)0.f; pb.h[14] = (_Float16)0.f; pb.h[15] = (_Float16)0.f;
        int tile = t >> 5, pos = t & 31;
        ((uint4*)BpkY)[tile * 64 + pos]      = pb.u[0];
        ((uint4*)BpkY)[tile * 64 + 32 + pos] = pb.u[1];
        // A-pack of Y
        float ax = -2.f * x, ay = -2.f * y, az = -2.f * z;
        _Float16 ahx = (_Float16)ax, ahy = (_Float16)ay, ahz = (_Float16)az;
        pa.h[0] = ahx; pa.h[1] = ahy; pa.h[2] = ahz;
        pa.h[3] = (_Float16)(ax - (float)ahx);
        pa.h[4] = (_Float16)(ay - (float)ahy);
        pa.h[5] = (_Float16)(az - (float)ahz);
        pa.h[6] = ahx; pa.h[7] = ahy; pa.h[8] = ahz;
        pa.h[9] = wh; pa.h[10] = (_Float16)(w - (float)wh);
        pa.h[11] = (_Float16)1.f; pa.h[12] = (_Float16)1.f;
        pa.h[13] = (_Float16)0.f; pa.h[14] = (_Float16)0.f; pa.h[15] = (_Float16)0.f;
        ((uint4*)(ApkY + (size_t)t * 32))[0] = pa.u[0];
        ((uint4*)(ApkY + (size_t)t * 32))[1] = pa.u[1];
    } else if (idx < NX + NY + NM) {
        mins[idx - NX - NY] = __uint_as_float(0x7F800000u);  // +inf
    }
}

// 1536 blocks: [ts(2)][qs(16)][h(3)][b(8)][dir(2)]
// Block: 4 waves x 64 queries (2 A-frags). 2048 targets = 64 B-tiles =
// 4 groups of 16 tiles (16 KB), double-buffered in LDS via
// global_load_lds DMA (zero register cost for in-flight data; m97 pattern).
// One __syncthreads per group; compiler manages all waitcnts (R12 lesson:
// no inline asm). Stage(g+1) issued at top of compute(g) -> latency hidden.
__global__ __launch_bounds__(256, 2) void chamfer_kernel(const char* __restrict__ ApkX,
                                                         const char* __restrict__ BpkX,
                                                         const char* __restrict__ ApkY,
                                                         const char* __restrict__ BpkY,
                                                         float* __restrict__ mins)
{
    __shared__ __align__(16) char smem[2][16384];

    int bid = blockIdx.x;
    int ts = bid & 1;
    int qs = (bid >> 1) & 15;
    int rest = bid >> 5;        // 0..47
    int hh = rest % 3;
    int tmp = rest / 3;         // 0..15
    int b = tmp & 7;
    int dir = tmp >> 3;

    int tid = threadIdx.x;
    int w = tid >> 6;
    int lane = tid & 63;
    int l31 = lane & 31, kb = lane >> 5;

    const char* Aq;
    const char* Bt;
    float* mq_base;
    if (dir == 0) {
        Aq = ApkX + (size_t)b * N * 32;
        Bt = BpkY + (size_t)(b * H + hh) * N * 32;
        mq_base = mins + (size_t)(b * H + hh) * N;
    } else {
        Aq = ApkY + (size_t)(b * H + hh) * N * 32;
        Bt = BpkX + (size_t)b * N * 32;
        mq_base = mins + (size_t)B * H * N + (size_t)(b * H + hh) * N;
    }
    int qbase = qs * 256 + w * 64;
    Aq += (size_t)qbase * 32;
    Bt += (size_t)ts * 2048 * 32;

    f16x8 A0 = *(const f16x8*)(Aq + ((size_t)(l31)) * 32 + kb * 16);
    f16x8 A1 = *(const f16x8*)(Aq + ((size_t)(32 + l31)) * 32 + kb * 16);

    f32x16 mq0, mq1;
    #pragma unroll
    for (int r = 0; r < 16; ++r) { mq0[r] = INFINITY; mq1[r] = INFINITY; }

    // DMA staging: wave w stages 4 KB (tiles 4w..4w+3 of the group).
    // LDS dest is wave-uniform base + lane*16 (linear); global layout is
    // already tile-split so the LDS image is the conflict-free layout.
    #define STAGE(g, buf)                                                                 \
        {                                                                                 \
            char* dst0 = &smem[buf][w * 4096];                                            \
            const char* src0 = Bt + (size_t)(g) * 16384 + w * 4096 + (size_t)lane * 16;   \
            _Pragma("unroll")                                                             \
            for (int i = 0; i < 4; ++i)                                                   \
                __builtin_amdgcn_global_load_lds(                                         \
                    (const __attribute__((address_space(1))) void*)(src0 + (size_t)i * 1024), \
                    (__attribute__((address_space(3))) void*)(dst0 + i * 1024),           \
                    16, 0, 0);                                                            \
        }

    STAGE(0, 0);
    __syncthreads();

    f32x16 zero = {};
    for (int g = 0; g < 4; ++g) {
        if (g < 3) STAGE(g + 1, (g + 1) & 1);   // issue next group's DMA now

        const char* lb = &smem[g & 1][(size_t)kb * 512 + (size_t)l31 * 16];
        #pragma unroll
        for (int p = 0; p < 8; ++p) {
            f16x8 B0 = *(const f16x8*)(lb + (size_t)(2 * p) * 1024);
            f16x8 B1 = *(const f16x8*)(lb + (size_t)(2 * p + 1) * 1024);
            f32x16 D0 = __builtin_amdgcn_mfma_f32_32x32x16_f16(A0, B0, zero, 0, 0, 0);
            f32x16 D1 = __builtin_amdgcn_mfma_f32_32x32x16_f16(A0, B1, zero, 0, 0, 0);
            #pragma unroll
            for (int r = 0; r < 16; ++r)
                mq0[r] = fminf(mq0[r], fminf(D0[r], D1[r]));   // v_min3_f32
            f32x16 D2 = __builtin_amdgcn_mfma_f32_32x32x16_f16(A1, B0, zero, 0, 0, 0);
            f32x16 D3 = __builtin_amdgcn_mfma_f32_32x32x16_f16(A1, B1, zero, 0, 0, 0);
            #pragma unroll
            for (int r = 0; r < 16; ++r)
                mq1[r] = fminf(mq1[r], fminf(D2[r], D3[r]));   // v_min3_f32
        }
        __syncthreads();   // drains DMA (vmcnt) + read/write hazards
    }
    #undef STAGE

    // reduce each query row across the 32 columns (lanes), then global atomicMin
    #pragma unroll
    for (int a = 0; a < 2; ++a) {
        #pragma unroll
        for (int r = 0; r < 16; ++r) {
            float v = (a == 0) ? mq0[r] : mq1[r];
            v = fminf(v, __shfl_xor(v, 1, 64));
            v = fminf(v, __shfl_xor(v, 2, 64));
            v = fminf(v, __shfl_xor(v, 4, 64));
            v = fminf(v, __shfl_xor(v, 8, 64));
            v = fminf(v, __shfl_xor(v, 16, 64));
            if (l31 == 0) {
                int row = (r & 3) + 8 * (r >> 2) + 4 * kb;
                atomicMin((unsigned*)&mq_base[qbase + a * 32 + row],
                          __float_as_uint(fmaxf(v, 0.f)));
            }
        }
    }
}

__global__ void reduce_kernel(const float* __restrict__ mins, float* __restrict__ out)
{
    int tid = blockIdx.x * blockDim.x + threadIdx.x;  // 192*256 = 49152 threads
    float s = 0.f;
    #pragma unroll
    for (int k = 0; k < 4; ++k) s += mins[tid + k * 49152];
    #pragma unroll
    for (int off = 32; off > 0; off >>= 1) s += __shfl_down(s, off);
    if ((threadIdx.x & 63) == 0) atomicAdd(out, s);
}

extern "C" void kernel_launch(void* const* d_in, const int* in_sizes, int n_in,
                              void* d_out, int out_size, void* d_ws, size_t ws_size,
                              hipStream_t stream)
{
    const float* pts = (const float*)d_in[0];   // (8,4096,3) fp32
    const float* yp  = (const float*)d_in[1];   // (8,3,4) fp32
    float* out = (float*)d_out;
    float* ws  = (float*)d_ws;

    char* ApkX = (char*)ws;                     // 1 MB
    char* BpkX = (char*)(ws + 262144);          // 1 MB
    char* ApkY = (char*)(ws + 524288);          // 3 MB
    char* BpkY = (char*)(ws + 1310720);         // 3 MB
    float* mins = ws + 2097152;                 // 196608 floats

    prep_kernel<<<1280, 256, 0, stream>>>(pts, yp, ApkX, BpkX, ApkY, BpkY, mins, out);
    chamfer_kernel<<<1536, 256, 0, stream>>>(ApkX, BpkX, ApkY, BpkY, mins);
    reduce_kernel<<<192, 256, 0, stream>>>(mins, out);
}

// Round 16
// 65.292 us; speedup vs baseline: 31.6346x; 1.1961x over previous
//
#include <hip/hip_runtime.h>
#include <math.h>

#define REG_COEF 25.0f
#define B 8
#define H 3
#define N 4096

typedef _Float16 f16x8 __attribute__((ext_vector_type(8)));
typedef float f32x16 __attribute__((ext_vector_type(16)));

static constexpr int NX = B * N;          // 32768 sample points
static constexpr int NY = B * H * N;      // 98304 reflected points
static constexpr int NM = 2 * B * H * N;  // 196608 per-point mins

// Packed fragments for mfma_f32_32x32x16_f16 (32 B per point, 16 f16 slots):
//  A-pack (query, a=-2p): [ah(3) | al(3) | ah(3) | wh,wl | 1,1 | 0,0,0]
//  B-pack (target):       [th(3) | th(3) | tl(3) | 1,1 | twh,twl | 0,0,0]
//  dot(A,B) ~= |q-t|^2  (f16 hi/lo split, ~1e-4 abs err; verified R7-R15)
// ws layout (float units):
//   [0,       262144)  : ApkX   (1 MB)
//   [262144,  524288)  : BpkX   (1 MB)
//   [524288, 1310720)  : ApkY   (3 MB)
//   [1310720,2097152)  : BpkY   (3 MB)
//   [2097152,2293760)  : mins   (196608 floats)  (absorbs 2KB prefetch overread)

__global__ void prep_kernel(const float* __restrict__ pts, const float* __restrict__ ypred,
                            char* __restrict__ ApkX, char* __restrict__ BpkX,
                            char* __restrict__ ApkY, char* __restrict__ BpkY,
                            float* __restrict__ mins, float* __restrict__ out)
{
    int idx = blockIdx.x * blockDim.x + threadIdx.x;
    if (idx == 0) {
        float reg = 0.f;
        for (int b = 0; b < B; ++b) {
            float n[H][3];
            #pragma unroll
            for (int h = 0; h < H; ++h) {
                float a0 = ypred[b * 12 + h * 4 + 0];
                float a1 = ypred[b * 12 + h * 4 + 1];
                float a2 = ypred[b * 12 + h * 4 + 2];
                float inv = rsqrtf(a0 * a0 + a1 * a1 + a2 * a2);
                n[h][0] = a0 * inv; n[h][1] = a1 * inv; n[h][2] = a2 * inv;
            }
            float s = 0.f;
            #pragma unroll
            for (int c = 0; c < H; ++c)
                #pragma unroll
                for (int e = 0; e < H; ++e) {
                    float g = n[c][0] * n[e][0] + n[c][1] * n[e][1] + n[c][2] * n[e][2];
                    if (c == e) g -= 1.f;
                    s += g * g;
                }
            reg += sqrtf(s);
        }
        out[0] = REG_COEF * reg;   // reduce_kernel accumulates on top
    }

    union { _Float16 h[16]; uint4 u[2]; } pa, pb;

    if (idx < NX) {
        const float* p = pts + (size_t)idx * 3;
        float x = p[0], y = p[1], z = p[2];
        float w = x * x + y * y + z * z;
        // A-pack of X
        float ax = -2.f * x, ay = -2.f * y, az = -2.f * z;
        _Float16 ahx = (_Float16)ax, ahy = (_Float16)ay, ahz = (_Float16)az;
        _Float16 wh = (_Float16)w;
        pa.h[0] = ahx; pa.h[1] = ahy; pa.h[2] = ahz;
        pa.h[3] = (_Float16)(ax - (float)ahx);
        pa.h[4] = (_Float16)(ay - (float)ahy);
        pa.h[5] = (_Float16)(az - (float)ahz);
        pa.h[6] = ahx; pa.h[7] = ahy; pa.h[8] = ahz;
        pa.h[9] = wh; pa.h[10] = (_Float16)(w - (float)wh);
        pa.h[11] = (_Float16)1.f; pa.h[12] = (_Float16)1.f;
        pa.h[13] = (_Float16)0.f; pa.h[14] = (_Float16)0.f; pa.h[15] = (_Float16)0.f;
        ((uint4*)(ApkX + (size_t)idx * 32))[0] = pa.u[0];
        ((uint4*)(ApkX + (size_t)idx * 32))[1] = pa.u[1];
        // B-pack of X
        _Float16 thx = (_Float16)x, thy = (_Float16)y, thz = (_Float16)z;
        pb.h[0] = thx; pb.h[1] = thy; pb.h[2] = thz;
        pb.h[3] = thx; pb.h[4] = thy; pb.h[5] = thz;
        pb.h[6] = (_Float16)(x - (float)thx);
        pb.h[7] = (_Float16)(y - (float)thy);
        pb.h[8] = (_Float16)(z - (float)thz);
        pb.h[9] = (_Float16)1.f; pb.h[10] = (_Float16)1.f;
        pb.h[11] = wh; pb.h[12] = (_Float16)(w - (float)wh);
        pb.h[13] = (_Float16)0.f; pb.h[14] = (_Float16)0.f; pb.h[15] = (_Float16)0.f;
        ((uint4*)(BpkX + (size_t)idx * 32))[0] = pb.u[0];
        ((uint4*)(BpkX + (size_t)idx * 32))[1] = pb.u[1];
    } else if (idx < NX + NY) {
        int t = idx - NX;            // (b*H + h)*N + nn
        int nn = t & (N - 1);
        int bh = t >> 12;
        int b = bh / H, h = bh - b * H;
        float a0 = ypred[b * 12 + h * 4 + 0];
        float a1 = ypred[b * 12 + h * 4 + 1];
        float a2 = ypred[b * 12 + h * 4 + 2];
        float off = ypred[b * 12 + h * 4 + 3];
        float inv = rsqrtf(a0 * a0 + a1 * a1 + a2 * a2);
        a0 *= inv; a1 *= inv; a2 *= inv;
        const float* p = pts + ((size_t)b * N + nn) * 3;
        float x0 = p[0], x1 = p[1], x2 = p[2];
        float dist = a0 * x0 + a1 * x1 + a2 * x2 + off;
        float x = fmaf(-2.f * dist, a0, x0);
        float y = fmaf(-2.f * dist, a1, x1);
        float z = fmaf(-2.f * dist, a2, x2);
        float w = x * x + y * y + z * z;
        // B-pack of Y
        _Float16 thx = (_Float16)x, thy = (_Float16)y, thz = (_Float16)z;
        _Float16 wh = (_Float16)w;
        pb.h[0] = thx; pb.h[1] = thy; pb.h[2] = thz;
        pb.h[3] = thx; pb.h[4] = thy; pb.h[5] = thz;
        pb.h[6] = (_Float16)(x - (float)thx);
        pb.h[7] = (_Float16)(y - (float)thy);
        pb.h[8] = (_Float16)(z - (float)thz);
        pb.h[9] = (_Float16)1.f; pb.h[10] = (_Float16)1.f;
        pb.h[11] = wh; pb.h[12] = (_Float16)(w - (float)wh);
        pb.h[13] = (_Float16)0.f; pb.h[14] = (_Float16)0.f; pb.h[15] = (_Float16)0.f;
        ((uint4*)(BpkY + (size_t)t * 32))[0] = pb.u[0];
        ((uint4*)(BpkY + (size_t)t * 32))[1] = pb.u[1];
        // A-pack of Y
        float ax = -2.f * x, ay = -2.f * y, az = -2.f * z;
        _Float16 ahx = (_Float16)ax, ahy = (_Float16)ay, ahz = (_Float16)az;
        pa.h[0] = ahx; pa.h[1] = ahy; pa.h[2] = ahz;
        pa.h[3] = (_Float16)(ax - (float)ahx);
        pa.h[4] = (_Float16)(ay - (float)ahy);
        pa.h[5] = (_Float16)(az - (float)ahz);
        pa.h[6] = ahx; pa.h[7] = ahy; pa.h[8] = ahz;
        pa.h[9] = wh; pa.h[10] = (_Float16)(w - (float)wh);
        pa.h[11] = (_Float16)1.f; pa.h[12] = (_Float16)1.f;
        pa.h[13] = (_Float16)0.f; pa.h[14] = (_Float16)0.f; pa.h[15] = (_Float16)0.f;
        ((uint4*)(ApkY + (size_t)t * 32))[0] = pa.u[0];
        ((uint4*)(ApkY + (size_t)t * 32))[1] = pa.u[1];
    } else if (idx < NX + NY + NM) {
        mins[idx - NX - NY] = __uint_as_float(0x7F800000u);  // +inf
    }
}

// 1536 blocks: [ts(2)][qs(16)][h(3)][b(8)][dir(2)]
// Block: 4 waves x 64 queries (2 A-frags), streams 2048 targets as 64
// 32-wide B-tiles, processed in PAIRS with pair-depth prefetch:
// only 4 B-tiles (16 VGPR) live -> total regs ~104 < 128 -> 4 waves/SIMD
// (R9 kept 8 tiles live = 32 regs -> >128 -> 2 waves/SIMD; R15 lesson).
__global__ __launch_bounds__(256, 4) void chamfer_kernel(const char* __restrict__ ApkX,
                                                         const char* __restrict__ BpkX,
                                                         const char* __restrict__ ApkY,
                                                         const char* __restrict__ BpkY,
                                                         float* __restrict__ mins)
{
    int bid = blockIdx.x;
    int ts = bid & 1;
    int qs = (bid >> 1) & 15;
    int rest = bid >> 5;        // 0..47
    int hh = rest % 3;
    int tmp = rest / 3;         // 0..15
    int b = tmp & 7;
    int dir = tmp >> 3;

    int tid = threadIdx.x;
    int w = tid >> 6;
    int lane = tid & 63;
    int l31 = lane & 31, kb = lane >> 5;

    const char* Aq;
    const char* Bt;
    float* mq_base;
    if (dir == 0) {
        Aq = ApkX + (size_t)b * N * 32;
        Bt = BpkY + (size_t)(b * H + hh) * N * 32;
        mq_base = mins + (size_t)(b * H + hh) * N;
    } else {
        Aq = ApkY + (size_t)(b * H + hh) * N * 32;
        Bt = BpkX + (size_t)b * N * 32;
        mq_base = mins + (size_t)B * H * N + (size_t)(b * H + hh) * N;
    }
    int qbase = qs * 256 + w * 64;
    Aq += (size_t)qbase * 32;
    Bt += (size_t)ts * 2048 * 32;

    f16x8 A0 = *(const f16x8*)(Aq + ((size_t)(l31)) * 32 + kb * 16);
    f16x8 A1 = *(const f16x8*)(Aq + ((size_t)(32 + l31)) * 32 + kb * 16);

    f32x16 mq0, mq1;
    #pragma unroll
    for (int r = 0; r < 16; ++r) { mq0[r] = INFINITY; mq1[r] = INFINITY; }

    const char* Bp = Bt + (size_t)l31 * 32 + kb * 16;
    f16x8 B0 = *(const f16x8*)(Bp);
    f16x8 B1 = *(const f16x8*)(Bp + 1024);
    f32x16 zero = {};

    for (int bt = 0; bt < 64; bt += 2) {
        // prefetch next pair (last iter overreads 2KB into adjacent ws; unused)
        f16x8 N0 = *(const f16x8*)(Bp + (size_t)(bt + 2) * 1024);
        f16x8 N1 = *(const f16x8*)(Bp + (size_t)(bt + 3) * 1024);
        f32x16 D0 = __builtin_amdgcn_mfma_f32_32x32x16_f16(A0, B0, zero, 0, 0, 0);
        f32x16 D1 = __builtin_amdgcn_mfma_f32_32x32x16_f16(A0, B1, zero, 0, 0, 0);
        #pragma unroll
        for (int r = 0; r < 16; ++r)
            mq0[r] = fminf(mq0[r], fminf(D0[r], D1[r]));   // v_min3_f32
        f32x16 D2 = __builtin_amdgcn_mfma_f32_32x32x16_f16(A1, B0, zero, 0, 0, 0);
        f32x16 D3 = __builtin_amdgcn_mfma_f32_32x32x16_f16(A1, B1, zero, 0, 0, 0);
        #pragma unroll
        for (int r = 0; r < 16; ++r)
            mq1[r] = fminf(mq1[r], fminf(D2[r], D3[r]));   // v_min3_f32
        B0 = N0; B1 = N1;
    }

    // reduce each query row across the 32 columns (lanes), then global atomicMin
    #pragma unroll
    for (int a = 0; a < 2; ++a) {
        #pragma unroll
        for (int r = 0; r < 16; ++r) {
            float v = (a == 0) ? mq0[r] : mq1[r];
            v = fminf(v, __shfl_xor(v, 1, 64));
            v = fminf(v, __shfl_xor(v, 2, 64));
            v = fminf(v, __shfl_xor(v, 4, 64));
            v = fminf(v, __shfl_xor(v, 8, 64));
            v = fminf(v, __shfl_xor(v, 16, 64));
            if (l31 == 0) {
                int row = (r & 3) + 8 * (r >> 2) + 4 * kb;
                atomicMin((unsigned*)&mq_base[qbase + a * 32 + row],
                          __float_as_uint(fmaxf(v, 0.f)));
            }
        }
    }
}

__global__ void reduce_kernel(const float* __restrict__ mins, float* __restrict__ out)
{
    int tid = blockIdx.x * blockDim.x + threadIdx.x;  // 192*256 = 49152 threads
    float s = 0.f;
    #pragma unroll
    for (int k = 0; k < 4; ++k) s += mins[tid + k * 49152];
    #pragma unroll
    for (int off = 32; off > 0; off >>= 1) s += __shfl_down(s, off);
    if ((threadIdx.x & 63) == 0) atomicAdd(out, s);
}

extern "C" void kernel_launch(void* const* d_in, const int* in_sizes, int n_in,
                              void* d_out, int out_size, void* d_ws, size_t ws_size,
                              hipStream_t stream)
{
    const float* pts = (const float*)d_in[0];   // (8,4096,3) fp32
    const float* yp  = (const float*)d_in[1];   // (8,3,4) fp32
    float* out = (float*)d_out;
    float* ws  = (float*)d_ws;

    char* ApkX = (char*)ws;                     // 1 MB
    char* BpkX = (char*)(ws + 262144);          // 1 MB
    char* ApkY = (char*)(ws + 524288);          // 3 MB
    char* BpkY = (char*)(ws + 1310720);         // 3 MB
    float* mins = ws + 2097152;                 // 196608 floats

    prep_kernel<<<1280, 256, 0, stream>>>(pts, yp, ApkX, BpkX, ApkY, BpkY, mins, out);
    chamfer_kernel<<<1536, 256, 0, stream>>>(ApkX, BpkX, ApkY, BpkY, mins);
    reduce_kernel<<<192, 256, 0, stream>>>(mins, out);
}